// Round 7
// baseline (60.463 us; speedup 1.0000x reference)
//
#include <hip/hip_runtime.h>

// Problem constants (match reference)
#define NB 32768
#define ND 512
#define NK 10

#define LEFTB (-10.0f)
#define RIGHTB (10.0f)
#define ROWS 8
#define BX 1024     // grid = (BX, 4); block = 128 threads = 128 features
#define FPB 128     // features per block

// ---------------------------------------------------------------------------
// Workspace layout (floats):
//   E    [ 9][512]          internal knots cw[1..9] (register bin search)
//   GBIN [10][512] float4   {cw_k, 1/w_k, ch_k, h_k}
//   GDP  [10][512] float2   {d_k, d_{k+1}}
//   part [NB][32]           per-row partial sums for logdet
// ---------------------------------------------------------------------------
#define OFF_BIN (9 * ND)                 // floats
#define OFF_DP  (OFF_BIN + NK * ND * 4)  // floats
#define OFF_PART (OFF_DP + NK * ND * 2)  // floats

__global__ void rqs_precompute(const float* __restrict__ uw,
                               const float* __restrict__ uh,
                               const float* __restrict__ ud,
                               float* __restrict__ ws) {
    int f = blockIdx.x * blockDim.x + threadIdx.x;
    if (f >= ND) return;

    float* E = ws;
    float4* GBIN = (float4*)(ws + OFF_BIN);
    float2* GDP = (float2*)(ws + OFF_DP);

    float cw[NK + 1], ch[NK + 1], dd[NK + 1];

    // ---- widths -> x-knots ----
    {
        float u[NK];
        float m = -1e30f;
#pragma unroll
        for (int k = 0; k < NK; ++k) { u[k] = uw[f * NK + k]; m = fmaxf(m, u[k]); }
        float s = 0.0f;
#pragma unroll
        for (int k = 0; k < NK; ++k) { u[k] = expf(u[k] - m); s += u[k]; }
        float inv = 1.0f / s;
        float c = 0.0f;
        cw[0] = LEFTB;
#pragma unroll
        for (int k = 0; k < NK; ++k) {
            float wk = 1e-3f + (1.0f - 1e-3f * NK) * (u[k] * inv);
            c += wk;
            cw[k + 1] = (RIGHTB - LEFTB) * c + LEFTB;
        }
        cw[NK] = RIGHTB;
    }
    // ---- heights -> y-knots ----
    {
        float u[NK];
        float m = -1e30f;
#pragma unroll
        for (int k = 0; k < NK; ++k) { u[k] = uh[f * NK + k]; m = fmaxf(m, u[k]); }
        float s = 0.0f;
#pragma unroll
        for (int k = 0; k < NK; ++k) { u[k] = expf(u[k] - m); s += u[k]; }
        float inv = 1.0f / s;
        float c = 0.0f;
        ch[0] = LEFTB;
#pragma unroll
        for (int k = 0; k < NK; ++k) {
            float hk = 1e-3f + (1.0f - 1e-3f * NK) * (u[k] * inv);
            c += hk;
            ch[k + 1] = (RIGHTB - LEFTB) * c + LEFTB;
        }
        ch[NK] = RIGHTB;
    }
    // ---- derivatives: boundary pads are exactly 1.0 ----
    dd[0] = 1.0f;
    dd[NK] = 1.0f;
#pragma unroll
    for (int k = 1; k < NK; ++k) {
        float v = ud[f * (NK - 1) + (k - 1)];
        dd[k] = 1e-3f + (fmaxf(v, 0.0f) + log1pf(expf(-fabsf(v))));
    }

    // ---- store ----
#pragma unroll
    for (int j = 0; j < 9; ++j) E[j * ND + f] = cw[j + 1];
#pragma unroll
    for (int k = 0; k < NK; ++k) {
        float w = cw[k + 1] - cw[k];
        float h = ch[k + 1] - ch[k];
        GBIN[k * ND + f] = make_float4(cw[k], 1.0f / w, ch[k], h);
        GDP[k * ND + f] = make_float2(dd[k], dd[k + 1]);
    }
}

// ---------------------------------------------------------------------------
// Main transform. Block = 128 threads = 128 features (quarter = blockIdx.y).
// LDS [bin][FPB] planes (stride multiple of 32 banks -> idx gather is
// conflict-free). Per element: 1 ds_read_b128 + 1 ds_read_b64, no derivation
// math, no clamp (outside lanes select x / 0 at the end).
// ---------------------------------------------------------------------------
__global__ __launch_bounds__(128) void rqs_main(const float* __restrict__ X,
                                                const float* __restrict__ ws,
                                                float* __restrict__ Y,
                                                float* __restrict__ part) {
    const int t = threadIdx.x;
    const int q = blockIdx.y;        // feature quarter 0..3
    const int f = q * FPB + t;

    const float* E = ws;
    const float4* GBIN = (const float4*)(ws + OFF_BIN);
    const float2* GDP = (const float2*)(ws + OFF_DP);

    __shared__ float4 sBIN[NK][FPB];  // 20480 B
    __shared__ float2 sDP[NK][FPB];   // 10240 B

#pragma unroll
    for (int k = 0; k < NK; ++k) {
        sBIN[k][t] = GBIN[k * ND + f];
        sDP[k][t] = GDP[k * ND + f];
    }
    float e[9];
#pragma unroll
    for (int j = 0; j < 9; ++j) e[j] = E[j * ND + f];
    __syncthreads();

    const int step = gridDim.x * ROWS;
    int r0 = blockIdx.x * ROWS;

    float xs[ROWS];
#pragma unroll
    for (int i = 0; i < ROWS; ++i)
        xs[i] = __builtin_nontemporal_load(&X[(r0 + i) * ND + f]);

    for (; r0 < NB; r0 += step) {
        // prefetch next batch before computing on current
        float xn[ROWS];
        const int rn = r0 + step;
        if (rn < NB) {
#pragma unroll
            for (int i = 0; i < ROWS; ++i)
                xn[i] = __builtin_nontemporal_load(&X[(rn + i) * ND + f]);
        }

        float ys[ROWS], ls[ROWS];
#pragma unroll
        for (int i = 0; i < ROWS; ++i) {
            float x = xs[i];

            int idx = 0;
#pragma unroll
            for (int j = 0; j < 9; ++j) idx += (x >= e[j]) ? 1 : 0;

            float4 bb = sBIN[idx][t];   // {cw, 1/w, ch, h}
            float2 dp = sDP[idx][t];    // {dk, dk1}

            float delta = bb.w * bb.y;
            float theta = (x - bb.x) * bb.y;
            float omt = 1.0f - theta;
            float t1m = theta * omt;
            float th2 = theta * theta;

            float num = bb.w * fmaf(delta, th2, dp.x * t1m);
            float den = fmaf(dp.x + dp.y - 2.0f * delta, t1m, delta);
            float rden = __builtin_amdgcn_rcpf(den);  // den > 0 for inside lanes
            float y = fmaf(num, rden, bb.z);

            float dnum = delta * delta *
                         (fmaf(dp.y, th2, 2.0f * delta * t1m) + dp.x * omt * omt);
            float lad = __logf(dnum * rden * rden);   // log(dnum) - 2 log(den)

            bool inside = fabsf(x) <= RIGHTB;         // abs is a free src modifier
            ys[i] = inside ? y : x;
            ls[i] = inside ? lad : 0.0f;
        }

#pragma unroll
        for (int i = 0; i < ROWS; ++i)
            __builtin_nontemporal_store(ys[i], &Y[(r0 + i) * ND + f]);

        // 4-level xor reduce -> 8 partials per row-quarter
#pragma unroll
        for (int off = 1; off <= 8; off <<= 1) {
#pragma unroll
            for (int i = 0; i < ROWS; ++i) ls[i] += __shfl_xor(ls[i], off, 64);
        }
        if ((t & 15) == 0) {
            int g = q * 8 + (t >> 4);  // 0..31 across the four quarters
#pragma unroll
            for (int i = 0; i < ROWS; ++i) part[(r0 + i) * 32 + g] = ls[i];
        }

#pragma unroll
        for (int i = 0; i < ROWS; ++i) xs[i] = xn[i];
    }
}

// ---------------------------------------------------------------------------
// logdet = sum of 32 partials per row. 8 threads per row, float4.
// ---------------------------------------------------------------------------
__global__ __launch_bounds__(256) void rqs_reduce(const float* __restrict__ part,
                                                  float* __restrict__ logdet) {
    int j = blockIdx.x * 256 + threadIdx.x;
    int row = j >> 3;
    int sub = j & 7;
    float4 v = ((const float4*)part)[row * 8 + sub];
    float s = (v.x + v.y) + (v.z + v.w);
    s += __shfl_xor(s, 1, 64);
    s += __shfl_xor(s, 2, 64);
    s += __shfl_xor(s, 4, 64);
    if (sub == 0) logdet[row] = s;
}

extern "C" void kernel_launch(void* const* d_in, const int* in_sizes, int n_in,
                              void* d_out, int out_size, void* d_ws, size_t ws_size,
                              hipStream_t stream) {
    const float* x  = (const float*)d_in[0];
    const float* uw = (const float*)d_in[1];
    const float* uh = (const float*)d_in[2];
    const float* ud = (const float*)d_in[3];

    float* out = (float*)d_out;
    float* Y = out;                              // [NB*ND]
    float* logdet = out + (size_t)NB * ND;       // [NB]

    float* ws = (float*)d_ws;
    float* part = ws + OFF_PART;                 // NB*32 floats (4 MB)

    hipLaunchKernelGGL(rqs_precompute, dim3(2), dim3(256), 0, stream,
                       uw, uh, ud, ws);
    hipLaunchKernelGGL(rqs_main, dim3(BX, 4), dim3(128), 0, stream,
                       x, ws, Y, part);
    hipLaunchKernelGGL(rqs_reduce, dim3(NB * 8 / 256), dim3(256), 0, stream,
                       part, logdet);
}

// Round 8
// 55.417 us; speedup vs baseline: 1.0910x; 1.0910x over previous
//
#include <hip/hip_runtime.h>

// Problem constants (match reference)
#define NB 32768
#define ND 512
#define NK 10

#define LEFTB (-10.0f)
#define RIGHTB (10.0f)
#define ROWS 8
#define BX 1024     // grid = (BX, 4); block = 128 threads = 128 features
#define FPB 128     // features per block

// ---------------------------------------------------------------------------
// Workspace layout (floats):
//   E    [ 9][512]          internal knots cw[1..9] (register bin search)
//   GKN  [11][512] float4   {cw_k, ch_k, d_k, 1/w_k}  (1/w invalid at k=10)
//   part [NB][32]           per-row partial sums for logdet
// ---------------------------------------------------------------------------
#define OFF_KN   (9 * ND)                      // floats
#define OFF_PART (OFF_KN + (NK + 1) * ND * 4)  // floats

__global__ void rqs_precompute(const float* __restrict__ uw,
                               const float* __restrict__ uh,
                               const float* __restrict__ ud,
                               float* __restrict__ ws) {
    int f = blockIdx.x * blockDim.x + threadIdx.x;
    if (f >= ND) return;

    float* E = ws;
    float4* GKN = (float4*)(ws + OFF_KN);

    float cw[NK + 1], ch[NK + 1], dd[NK + 1];

    // ---- widths -> x-knots ----
    {
        float u[NK];
        float m = -1e30f;
#pragma unroll
        for (int k = 0; k < NK; ++k) { u[k] = uw[f * NK + k]; m = fmaxf(m, u[k]); }
        float s = 0.0f;
#pragma unroll
        for (int k = 0; k < NK; ++k) { u[k] = expf(u[k] - m); s += u[k]; }
        float inv = 1.0f / s;
        float c = 0.0f;
        cw[0] = LEFTB;
#pragma unroll
        for (int k = 0; k < NK; ++k) {
            float wk = 1e-3f + (1.0f - 1e-3f * NK) * (u[k] * inv);
            c += wk;
            cw[k + 1] = (RIGHTB - LEFTB) * c + LEFTB;
        }
        cw[NK] = RIGHTB;
    }
    // ---- heights -> y-knots ----
    {
        float u[NK];
        float m = -1e30f;
#pragma unroll
        for (int k = 0; k < NK; ++k) { u[k] = uh[f * NK + k]; m = fmaxf(m, u[k]); }
        float s = 0.0f;
#pragma unroll
        for (int k = 0; k < NK; ++k) { u[k] = expf(u[k] - m); s += u[k]; }
        float inv = 1.0f / s;
        float c = 0.0f;
        ch[0] = LEFTB;
#pragma unroll
        for (int k = 0; k < NK; ++k) {
            float hk = 1e-3f + (1.0f - 1e-3f * NK) * (u[k] * inv);
            c += hk;
            ch[k + 1] = (RIGHTB - LEFTB) * c + LEFTB;
        }
        ch[NK] = RIGHTB;
    }
    // ---- derivatives: boundary pads are exactly 1.0 ----
    dd[0] = 1.0f;
    dd[NK] = 1.0f;
#pragma unroll
    for (int k = 1; k < NK; ++k) {
        float v = ud[f * (NK - 1) + (k - 1)];
        dd[k] = 1e-3f + (fmaxf(v, 0.0f) + log1pf(expf(-fabsf(v))));
    }

    // ---- store ----
#pragma unroll
    for (int j = 0; j < 9; ++j) E[j * ND + f] = cw[j + 1];
#pragma unroll
    for (int k = 0; k <= NK; ++k) {
        float rw = (k < NK) ? 1.0f / (cw[k + 1] - cw[k]) : 0.0f;
        GKN[k * ND + f] = make_float4(cw[k], ch[k], dd[k], rw);
    }
}

// ---------------------------------------------------------------------------
// Main transform. Block = 128 threads = 128 features (quarter = blockIdx.y).
// LDS [knot][FPB] float4 planes: plane stride 2048 B (bank-neutral) -> the
// per-lane idx gather is conflict-free. Per element: 2x ds_read_b128.
// No clamp: outside lanes compute garbage, final selects discard it.
// ---------------------------------------------------------------------------
__global__ __launch_bounds__(128) void rqs_main(const float* __restrict__ X,
                                                const float* __restrict__ ws,
                                                float* __restrict__ Y,
                                                float* __restrict__ part) {
    const int t = threadIdx.x;
    const int q = blockIdx.y;        // feature quarter 0..3
    const int f = q * FPB + t;

    const float* E = ws;
    const float4* GKN = (const float4*)(ws + OFF_KN);

    __shared__ float4 sKN[NK + 1][FPB];  // 22528 B

#pragma unroll
    for (int k = 0; k <= NK; ++k) sKN[k][t] = GKN[k * ND + f];

    float e[9];
#pragma unroll
    for (int j = 0; j < 9; ++j) e[j] = E[j * ND + f];
    __syncthreads();

    const int step = gridDim.x * ROWS;

    for (int r0 = blockIdx.x * ROWS; r0 < NB; r0 += step) {
        float xs[ROWS], ys[ROWS], ls[ROWS];
#pragma unroll
        for (int i = 0; i < ROWS; ++i)
            xs[i] = __builtin_nontemporal_load(&X[(r0 + i) * ND + f]);

#pragma unroll
        for (int i = 0; i < ROWS; ++i) {
            float x = xs[i];

            int idx = 0;
#pragma unroll
            for (int j = 0; j < 9; ++j) idx += (x >= e[j]) ? 1 : 0;

            float4 k0 = sKN[idx][t];      // {cw0, ch0, d0, 1/w}
            float4 k1 = sKN[idx + 1][t];  // {cw1, ch1, d1, -}

            float h = k1.y - k0.y;
            float delta = h * k0.w;
            float theta = (x - k0.x) * k0.w;
            float omt = 1.0f - theta;
            float t1m = theta * omt;
            float th2 = theta * theta;

            float num = h * fmaf(delta, th2, k0.z * t1m);
            float den = fmaf(fmaf(-2.0f, delta, k0.z + k1.z), t1m, delta);
            float rden = __builtin_amdgcn_rcpf(den);  // den > 0 for inside lanes
            float y = fmaf(num, rden, k0.y);

            float dnum = delta * delta *
                         (fmaf(k1.z, th2, 2.0f * delta * t1m) + k0.z * omt * omt);
            float lad = __logf(dnum * rden * rden);   // log(dnum) - 2 log(den)

            bool inside = fabsf(x) <= RIGHTB;         // abs = free src modifier
            ys[i] = inside ? y : x;
            ls[i] = inside ? lad : 0.0f;
        }

#pragma unroll
        for (int i = 0; i < ROWS; ++i)
            __builtin_nontemporal_store(ys[i], &Y[(r0 + i) * ND + f]);

        // 4-level xor reduce (DPP row ops) -> 8 partials per row-quarter
#pragma unroll
        for (int off = 1; off <= 8; off <<= 1) {
#pragma unroll
            for (int i = 0; i < ROWS; ++i) ls[i] += __shfl_xor(ls[i], off, 64);
        }
        if ((t & 15) == 0) {
            int g = q * 8 + (t >> 4);  // 0..31 across the four quarters
#pragma unroll
            for (int i = 0; i < ROWS; ++i) part[(r0 + i) * 32 + g] = ls[i];
        }
    }
}

// ---------------------------------------------------------------------------
// logdet = sum of 32 partials per row. 8 threads per row, float4.
// ---------------------------------------------------------------------------
__global__ __launch_bounds__(256) void rqs_reduce(const float* __restrict__ part,
                                                  float* __restrict__ logdet) {
    int j = blockIdx.x * 256 + threadIdx.x;
    int row = j >> 3;
    int sub = j & 7;
    float4 v = ((const float4*)part)[row * 8 + sub];
    float s = (v.x + v.y) + (v.z + v.w);
    s += __shfl_xor(s, 1, 64);
    s += __shfl_xor(s, 2, 64);
    s += __shfl_xor(s, 4, 64);
    if (sub == 0) logdet[row] = s;
}

extern "C" void kernel_launch(void* const* d_in, const int* in_sizes, int n_in,
                              void* d_out, int out_size, void* d_ws, size_t ws_size,
                              hipStream_t stream) {
    const float* x  = (const float*)d_in[0];
    const float* uw = (const float*)d_in[1];
    const float* uh = (const float*)d_in[2];
    const float* ud = (const float*)d_in[3];

    float* out = (float*)d_out;
    float* Y = out;                              // [NB*ND]
    float* logdet = out + (size_t)NB * ND;       // [NB]

    float* ws = (float*)d_ws;
    float* part = ws + OFF_PART;                 // NB*32 floats (4 MB)

    hipLaunchKernelGGL(rqs_precompute, dim3(4), dim3(128), 0, stream,
                       uw, uh, ud, ws);
    hipLaunchKernelGGL(rqs_main, dim3(BX, 4), dim3(128), 0, stream,
                       x, ws, Y, part);
    hipLaunchKernelGGL(rqs_reduce, dim3(NB * 8 / 256), dim3(256), 0, stream,
                       part, logdet);
}

// Round 9
// 45.921 us; speedup vs baseline: 1.3167x; 1.2068x over previous
//
#include <hip/hip_runtime.h>

// Problem constants (match reference)
#define NB 32768
#define ND 512
#define NK 10

#define LEFTB (-10.0f)
#define RIGHTB (10.0f)
#define ROWS 8
#define BX 512      // grid = (BX, 4); block = 128 threads = 128 features
#define FPB 128     // features per block

// ---------------------------------------------------------------------------
// Workspace layout (floats):
//   E     [ 9][512]          internal knots cw[1..9] (register bin search)
//   GCWCH [11][512] float2   {cw_k, ch_k} knot pairs
//   GDD   [11][512]          d_k
//   part  [NB][32]           per-row partial sums (in log2 units!)
// ---------------------------------------------------------------------------
#define OFF_CWCH (9 * ND)                   // floats
#define OFF_DD   (OFF_CWCH + 22 * ND)       // floats
#define OFF_PART (OFF_DD + 11 * ND)         // floats

__global__ void rqs_precompute(const float* __restrict__ uw,
                               const float* __restrict__ uh,
                               const float* __restrict__ ud,
                               float* __restrict__ ws) {
    int f = blockIdx.x * blockDim.x + threadIdx.x;
    if (f >= ND) return;

    float* E = ws;
    float2* GCWCH = (float2*)(ws + OFF_CWCH);
    float* GDD = ws + OFF_DD;

    float cw[NK + 1], ch[NK + 1], dd[NK + 1];

    // ---- widths -> x-knots ----
    {
        float u[NK];
        float m = -1e30f;
#pragma unroll
        for (int k = 0; k < NK; ++k) { u[k] = uw[f * NK + k]; m = fmaxf(m, u[k]); }
        float s = 0.0f;
#pragma unroll
        for (int k = 0; k < NK; ++k) { u[k] = expf(u[k] - m); s += u[k]; }
        float inv = 1.0f / s;
        float c = 0.0f;
        cw[0] = LEFTB;
#pragma unroll
        for (int k = 0; k < NK; ++k) {
            float wk = 1e-3f + (1.0f - 1e-3f * NK) * (u[k] * inv);
            c += wk;
            cw[k + 1] = (RIGHTB - LEFTB) * c + LEFTB;
        }
        cw[NK] = RIGHTB;
    }
    // ---- heights -> y-knots ----
    {
        float u[NK];
        float m = -1e30f;
#pragma unroll
        for (int k = 0; k < NK; ++k) { u[k] = uh[f * NK + k]; m = fmaxf(m, u[k]); }
        float s = 0.0f;
#pragma unroll
        for (int k = 0; k < NK; ++k) { u[k] = expf(u[k] - m); s += u[k]; }
        float inv = 1.0f / s;
        float c = 0.0f;
        ch[0] = LEFTB;
#pragma unroll
        for (int k = 0; k < NK; ++k) {
            float hk = 1e-3f + (1.0f - 1e-3f * NK) * (u[k] * inv);
            c += hk;
            ch[k + 1] = (RIGHTB - LEFTB) * c + LEFTB;
        }
        ch[NK] = RIGHTB;
    }
    // ---- derivatives: boundary pads are exactly 1.0 ----
    dd[0] = 1.0f;
    dd[NK] = 1.0f;
#pragma unroll
    for (int k = 1; k < NK; ++k) {
        float v = ud[f * (NK - 1) + (k - 1)];
        dd[k] = 1e-3f + (fmaxf(v, 0.0f) + log1pf(expf(-fabsf(v))));
    }

    // ---- store ----
#pragma unroll
    for (int j = 0; j < 9; ++j) E[j * ND + f] = cw[j + 1];
#pragma unroll
    for (int k = 0; k <= NK; ++k) {
        GCWCH[k * ND + f] = make_float2(cw[k], ch[k]);
        GDD[k * ND + f] = dd[k];
    }
}

// DPP row_shr:N add (VALU-only partial reduction within 16-lane rows).
__device__ __forceinline__ float dpp_row_reduce16(float v) {
    // after the 4 adds, lane (15 mod 16) holds the sum of its 16-lane row
    v += __int_as_float(__builtin_amdgcn_update_dpp(
        0, __float_as_int(v), 0x111, 0xF, 0xF, true));  // row_shr:1
    v += __int_as_float(__builtin_amdgcn_update_dpp(
        0, __float_as_int(v), 0x112, 0xF, 0xF, true));  // row_shr:2
    v += __int_as_float(__builtin_amdgcn_update_dpp(
        0, __float_as_int(v), 0x114, 0xF, 0xF, true));  // row_shr:4
    v += __int_as_float(__builtin_amdgcn_update_dpp(
        0, __float_as_int(v), 0x118, 0xF, 0xF, true));  // row_shr:8
    return v;
}

// ---------------------------------------------------------------------------
// Main transform. Block = 128 threads = 128 features (quarter = blockIdx.y).
// LDS [knot][FPB] float2/float planes (round-6 layout: measured 0 bank
// conflicts; knot pairs 1024/512 B apart -> ds_read2_b64 / ds_read2_b32).
// Per-element log in log2 units; ln2 applied once in rqs_reduce.
// Reduction is pure-VALU DPP (no ds_swizzle contention on the LDS pipe).
// ---------------------------------------------------------------------------
__global__ __launch_bounds__(128) void rqs_main(const float* __restrict__ X,
                                                const float* __restrict__ ws,
                                                float* __restrict__ Y,
                                                float* __restrict__ part) {
    const int t = threadIdx.x;
    const int q = blockIdx.y;        // feature quarter 0..3
    const int f = q * FPB + t;

    const float* E = ws;
    const float2* GCWCH = (const float2*)(ws + OFF_CWCH);
    const float* GDD = ws + OFF_DD;

    __shared__ float2 sCWCH[NK + 1][FPB];  // 11264 B
    __shared__ float sDD[NK + 1][FPB];     //  5632 B

#pragma unroll
    for (int k = 0; k <= NK; ++k) {
        sCWCH[k][t] = GCWCH[k * ND + f];
        sDD[k][t] = GDD[k * ND + f];
    }
    float e[9];
#pragma unroll
    for (int j = 0; j < 9; ++j) e[j] = E[j * ND + f];
    __syncthreads();

    const int step = gridDim.x * ROWS;

    for (int r0 = blockIdx.x * ROWS; r0 < NB; r0 += step) {
        float xs[ROWS], ys[ROWS], ls[ROWS];
#pragma unroll
        for (int i = 0; i < ROWS; ++i)
            xs[i] = __builtin_nontemporal_load(&X[(r0 + i) * ND + f]);

#pragma unroll
        for (int i = 0; i < ROWS; ++i) {
            float x = xs[i];

            // bin search on raw x: saturates to 0 / 9 outside, same as clamp
            int idx = 0;
#pragma unroll
            for (int j = 0; j < 9; ++j) idx += (x >= e[j]) ? 1 : 0;

            float2 c0 = sCWCH[idx][t];      // {cw_k,   ch_k}
            float2 c1 = sCWCH[idx + 1][t];  // {cw_k+1, ch_k+1}
            float dk = sDD[idx][t];
            float dk1 = sDD[idx + 1][t];

            float w = c1.x - c0.x;
            float rw = __builtin_amdgcn_rcpf(w);   // w >= 0.02 always
            float h = c1.y - c0.y;
            float delta = h * rw;

            float theta = (x - c0.x) * rw;
            float omt = 1.0f - theta;
            float t1m = theta * omt;
            float th2 = theta * theta;

            float num = h * fmaf(delta, th2, dk * t1m);
            float den = fmaf(fmaf(-2.0f, delta, dk + dk1), t1m, delta);
            float rden = __builtin_amdgcn_rcpf(den);  // den > 0 inside
            float y = fmaf(num, rden, c0.y);

            float dnum = delta * delta *
                         (fmaf(dk1, th2, 2.0f * delta * t1m) + dk * omt * omt);
            float lad2 = __log2f(dnum * rden * rden);  // log2; ln2 applied later

            bool inside = fabsf(x) <= RIGHTB;          // abs = free src modifier
            ys[i] = inside ? y : x;
            ls[i] = inside ? lad2 : 0.0f;
        }

#pragma unroll
        for (int i = 0; i < ROWS; ++i)
            __builtin_nontemporal_store(ys[i], &Y[(r0 + i) * ND + f]);

        // pure-VALU DPP reduce within 16-lane rows; lane 15 holds the sum
#pragma unroll
        for (int i = 0; i < ROWS; ++i) ls[i] = dpp_row_reduce16(ls[i]);
        if ((t & 15) == 15) {
            int g = q * 8 + (t >> 4);  // 0..31 across the four quarters
#pragma unroll
            for (int i = 0; i < ROWS; ++i) part[(r0 + i) * 32 + g] = ls[i];
        }
    }
}

// ---------------------------------------------------------------------------
// logdet = ln2 * sum of 32 log2-partials per row. 8 threads per row, float4.
// ---------------------------------------------------------------------------
__global__ __launch_bounds__(256) void rqs_reduce(const float* __restrict__ part,
                                                  float* __restrict__ logdet) {
    int j = blockIdx.x * 256 + threadIdx.x;
    int row = j >> 3;
    int sub = j & 7;
    float4 v = ((const float4*)part)[row * 8 + sub];
    float s = (v.x + v.y) + (v.z + v.w);
    s += __shfl_xor(s, 1, 64);
    s += __shfl_xor(s, 2, 64);
    s += __shfl_xor(s, 4, 64);
    if (sub == 0) logdet[row] = s * 0.6931471805599453f;
}

extern "C" void kernel_launch(void* const* d_in, const int* in_sizes, int n_in,
                              void* d_out, int out_size, void* d_ws, size_t ws_size,
                              hipStream_t stream) {
    const float* x  = (const float*)d_in[0];
    const float* uw = (const float*)d_in[1];
    const float* uh = (const float*)d_in[2];
    const float* ud = (const float*)d_in[3];

    float* out = (float*)d_out;
    float* Y = out;                              // [NB*ND]
    float* logdet = out + (size_t)NB * ND;       // [NB]

    float* ws = (float*)d_ws;
    float* part = ws + OFF_PART;                 // NB*32 floats (4 MB)

    hipLaunchKernelGGL(rqs_precompute, dim3(4), dim3(128), 0, stream,
                       uw, uh, ud, ws);
    hipLaunchKernelGGL(rqs_main, dim3(BX, 4), dim3(128), 0, stream,
                       x, ws, Y, part);
    hipLaunchKernelGGL(rqs_reduce, dim3(NB * 8 / 256), dim3(256), 0, stream,
                       part, logdet);
}